// Round 17
// baseline (72.866 us; speedup 1.0000x reference)
//
#include <hip/hip_runtime.h>
#include <hip/hip_fp16.h>

// Quant4Linear + EoRA fused GEMV, MI355X — atomic-free two-launch design.
//
// y[n] = bias[n] + scales[n]*sum_k x[k]*q[k,n] - zeros[n]*Sx + sum_r fp16(dp[r])*up[r,n]
//
// PROVEN: down/up are fp16 values in FLOAT32 carriers; d_in dict-order; out fp32.
// History: r5 283us; r6 43.8 (ILP); r9 37.3 (atomic-free); r10 null (TLP up);
// r11 32.2 (v_dot2); r12 30.8 (KCHUNKS 32); r13 null (balance); r15 141us
// (fused epilogue REVERTED: device fences = per-XCD L2 writeback storm);
// r16 30.17 (KCHUNKS 16). r17 (this): DRAM-contiguity probe — CPB 2048
// (8 cols/thread as two coalesced 4-col streams) doubles per-row-visit
// contiguity 4KB->8KB, halves row-jumps. KCHUNKS back to 32 for 448 quant
// blocks. If null -> declare roofline (access-pattern floor reached).

#define KDIM 8192
#define NDIM 28672
#define RDIM 64

#define KCHUNKS 32
#define KPC (KDIM / KCHUNKS)      // 256 k per quant chunk
#define KBPC (KPC / 8)            // 32 packed rows per chunk
#define CPB 2048                  // 256 threads x 8 cols (two 4-col groups)
#define NBLK (NDIM / CPB)         // 14
#define GOFF 1024                 // offset of the second 4-col group

#define PB 8                      // prep blocks
#define PKPB (KDIM / PB)          // 1024 k per prep block

#define QPART_FLOATS (KCHUNKS * NDIM)
#define DP_OFF QPART_FLOATS
#define WS_NEED ((QPART_FLOATS + PB * RDIM) * 4)

// fallback geometry (r5-proven)
#define FB_CPB 1024
#define FB_NBLK (NDIM / FB_CPB)   // 28

typedef _Float16 h2v __attribute__((ext_vector_type(2)));

// acc += fp16pair(up) . fp16pair(xp)   (fp32 accumulate)
__device__ __forceinline__ float dot2p(unsigned up, unsigned xp, float acc) {
#if __has_builtin(__builtin_amdgcn_fdot2)
    return __builtin_amdgcn_fdot2(__builtin_bit_cast(h2v, up),
                                  __builtin_bit_cast(h2v, xp), acc, false);
#else
    h2v a = __builtin_bit_cast(h2v, up);
    h2v b = __builtin_bit_cast(h2v, xp);
    return acc + (float)a.x * (float)b.x + (float)a.y * (float)b.y;
#endif
}

// ---------------------------------------------------------------------------
// Launch A: y<KCHUNKS -> quant chunk partials; y==KCHUNKS, x<PB -> dp partials.
// ---------------------------------------------------------------------------
__global__ __launch_bounds__(256, 8) void quant_kernel(const float* __restrict__ x,
                                                       const int* __restrict__ qw,
                                                       const float* __restrict__ scales,
                                                       const float* __restrict__ zeros,
                                                       const float* __restrict__ bias,
                                                       const float* __restrict__ down,
                                                       float* __restrict__ ws) {
    const int t  = threadIdx.x;
    const int ph = blockIdx.y;

    if (ph < KCHUNKS) {
        // ---------------- quant chunk: k in [ph*256, ph*256+256) ----------
        const int n0 = blockIdx.x * CPB + t * 4;         // group A cols
        const int n1 = n0 + GOFF;                        // group B cols
        const int* qp = qw + (size_t)(ph * KBPC) * NDIM;

        // prefetch batch 0 (rows 0-1, both groups) BEFORE the staging barrier
        int4 va0, vb0, va1, vb1;
        va0 = *(const int4*)(qp + n0);
        vb0 = *(const int4*)(qp + n1);
        va1 = *(const int4*)(qp + (size_t)NDIM + n0);
        vb1 = *(const int4*)(qp + (size_t)NDIM + n1);

        // stage x as fp16 pairs: xsp[row*4 + j] = half2(xh[row*8+j], xh[row*8+j+4])
        __shared__ __align__(16) unsigned xsp[KBPC * 4];
        __shared__ float sxs;
        if (t < KBPC) {                       // 32 threads, one packed row each
            const int base = ph * KPC + t * 8;
            const float4 f0 = *(const float4*)&x[base];
            const float4 f1 = *(const float4*)&x[base + 4];
            h2v p0 = { (_Float16)f0.x, (_Float16)f1.x };
            h2v p1 = { (_Float16)f0.y, (_Float16)f1.y };
            h2v p2 = { (_Float16)f0.z, (_Float16)f1.z };
            h2v p3 = { (_Float16)f0.w, (_Float16)f1.w };
            xsp[t * 4 + 0] = __builtin_bit_cast(unsigned, p0);
            xsp[t * 4 + 1] = __builtin_bit_cast(unsigned, p1);
            xsp[t * 4 + 2] = __builtin_bit_cast(unsigned, p2);
            xsp[t * 4 + 3] = __builtin_bit_cast(unsigned, p3);
            float s = (float)p0.x + (float)p0.y + (float)p1.x + (float)p1.y +
                      (float)p2.x + (float)p2.y + (float)p3.x + (float)p3.y;
            s += __shfl_down(s, 16, 32);
            s += __shfl_down(s, 8, 32);
            s += __shfl_down(s, 4, 32);
            s += __shfl_down(s, 2, 32);
            s += __shfl_down(s, 1, 32);
            if (t == 0) sxs = s;
        }
        __syncthreads();
        const float Sxh = sxs;

        const unsigned M = 0x000F000Fu;   // nibble pair (j, j+4)
        const unsigned E = 0x64006400u;   // fp16 exp 1024 -> value 1024+q

        float a0 = 0.f, a1 = 0.f, a2 = 0.f, a3 = 0.f;
        float b0 = 0.f, b1 = 0.f, b2 = 0.f, b3 = 0.f;

        // one int4 (4 cols) against x-row `xp`, into acc quad c0..c3
        #define DOTROW(vv, xp, c0, c1, c2, c3)                                \
        {                                                                     \
            const unsigned wx = (unsigned)vv.x;                               \
            const unsigned wy = (unsigned)vv.y;                               \
            const unsigned wz = (unsigned)vv.z;                               \
            const unsigned ww = (unsigned)vv.w;                               \
            c0 = dot2p((wx & M) | E, xp.x, c0);                               \
            c0 = dot2p(((wx >> 4) & M) | E, xp.y, c0);                        \
            c0 = dot2p(((wx >> 8) & M) | E, xp.z, c0);                        \
            c0 = dot2p(((wx >> 12) & M) | E, xp.w, c0);                       \
            c1 = dot2p((wy & M) | E, xp.x, c1);                               \
            c1 = dot2p(((wy >> 4) & M) | E, xp.y, c1);                        \
            c1 = dot2p(((wy >> 8) & M) | E, xp.z, c1);                        \
            c1 = dot2p(((wy >> 12) & M) | E, xp.w, c1);                       \
            c2 = dot2p((wz & M) | E, xp.x, c2);                               \
            c2 = dot2p(((wz >> 4) & M) | E, xp.y, c2);                        \
            c2 = dot2p(((wz >> 8) & M) | E, xp.z, c2);                        \
            c2 = dot2p(((wz >> 12) & M) | E, xp.w, c2);                       \
            c3 = dot2p((ww & M) | E, xp.x, c3);                               \
            c3 = dot2p(((ww >> 4) & M) | E, xp.y, c3);                        \
            c3 = dot2p(((ww >> 8) & M) | E, xp.z, c3);                        \
            c3 = dot2p(((ww >> 12) & M) | E, xp.w, c3);                       \
        }

        // consume batch 0 (rows 0,1)
        {
            const uint4 xp0 = *(const uint4*)&xsp[0];
            DOTROW(va0, xp0, a0, a1, a2, a3);
            DOTROW(vb0, xp0, b0, b1, b2, b3);
            const uint4 xp1 = *(const uint4*)&xsp[4];
            DOTROW(va1, xp1, a0, a1, a2, a3);
            DOTROW(vb1, xp1, b0, b1, b2, b3);
        }
        #pragma unroll
        for (int g = 1; g < KBPC / 2; ++g) {          // rows 2g, 2g+1
            const int r0 = g * 2;
            int4 wa0 = *(const int4*)(qp + (size_t)r0 * NDIM + n0);
            int4 wb0 = *(const int4*)(qp + (size_t)r0 * NDIM + n1);
            int4 wa1 = *(const int4*)(qp + (size_t)(r0 + 1) * NDIM + n0);
            int4 wb1 = *(const int4*)(qp + (size_t)(r0 + 1) * NDIM + n1);
            const uint4 xp0 = *(const uint4*)&xsp[r0 * 4];
            DOTROW(wa0, xp0, a0, a1, a2, a3);
            DOTROW(wb0, xp0, b0, b1, b2, b3);
            const uint4 xp1 = *(const uint4*)&xsp[(r0 + 1) * 4];
            DOTROW(wa1, xp1, a0, a1, a2, a3);
            DOTROW(wb1, xp1, b0, b1, b2, b3);
        }
        #undef DOTROW

        // remove the 1024-offset:  sum x*q = acc - 1024*Sxh
        const float corr = 1024.f * Sxh;
        {
            const float4 sc = *(const float4*)&scales[n0];
            const float4 zr = *(const float4*)&zeros[n0];
            float4 p;
            p.x = fmaf(sc.x, a0 - corr, -zr.x * Sxh);
            p.y = fmaf(sc.y, a1 - corr, -zr.y * Sxh);
            p.z = fmaf(sc.z, a2 - corr, -zr.z * Sxh);
            p.w = fmaf(sc.w, a3 - corr, -zr.w * Sxh);
            if (ph == 0) {
                const float4 bi = *(const float4*)&bias[n0];
                p.x += bi.x; p.y += bi.y; p.z += bi.z; p.w += bi.w;
            }
            *(float4*)&ws[(size_t)ph * NDIM + n0] = p;
        }
        {
            const float4 sc = *(const float4*)&scales[n1];
            const float4 zr = *(const float4*)&zeros[n1];
            float4 p;
            p.x = fmaf(sc.x, b0 - corr, -zr.x * Sxh);
            p.y = fmaf(sc.y, b1 - corr, -zr.y * Sxh);
            p.z = fmaf(sc.z, b2 - corr, -zr.z * Sxh);
            p.w = fmaf(sc.w, b3 - corr, -zr.w * Sxh);
            if (ph == 0) {
                const float4 bi = *(const float4*)&bias[n1];
                p.x += bi.x; p.y += bi.y; p.z += bi.z; p.w += bi.w;
            }
            *(float4*)&ws[(size_t)ph * NDIM + n1] = p;
        }
    } else if (blockIdx.x < PB) {
        // ---------------- prep: dp partials for k-block b -----------------
        const int b = blockIdx.x;
        const int w = t >> 6;
        const int l = t & 63;
        const int grp = l >> 4;
        const int li = l & 15;

        __shared__ float xsp2[PKPB];
        {
            float4 v = *(const float4*)&x[b * PKPB + t * 4];
            v.x = __half2float(__float2half(v.x));
            v.y = __half2float(__float2half(v.y));
            v.z = __half2float(__float2half(v.z));
            v.w = __half2float(__float2half(v.w));
            *(float4*)&xsp2[t * 4] = v;
        }
        __syncthreads();

        const float* dbase = down + (size_t)b * PKPB * RDIM;
        float a0 = 0.f, a1 = 0.f, a2 = 0.f, a3 = 0.f;
        for (int i = 0; i < 64; i += 4) {
            float4 v[4];
            #pragma unroll
            for (int u = 0; u < 4; ++u) {
                const int q = (i + u) * 4 + w;
                v[u] = *(const float4*)&dbase[(size_t)q * 256 + l * 4];
            }
            #pragma unroll
            for (int u = 0; u < 4; ++u) {
                const int q = (i + u) * 4 + w;
                const float xv = xsp2[q * 4 + grp];
                a0 = fmaf(xv, v[u].x, a0);
                a1 = fmaf(xv, v[u].y, a1);
                a2 = fmaf(xv, v[u].z, a2);
                a3 = fmaf(xv, v[u].w, a3);
            }
        }

        a0 += __shfl_xor(a0, 16, 64); a0 += __shfl_xor(a0, 32, 64);
        a1 += __shfl_xor(a1, 16, 64); a1 += __shfl_xor(a1, 32, 64);
        a2 += __shfl_xor(a2, 16, 64); a2 += __shfl_xor(a2, 32, 64);
        a3 += __shfl_xor(a3, 16, 64); a3 += __shfl_xor(a3, 32, 64);

        __shared__ float part[4][RDIM];
        if (l < 16) {
            part[w][li * 4 + 0] = a0;
            part[w][li * 4 + 1] = a1;
            part[w][li * 4 + 2] = a2;
            part[w][li * 4 + 3] = a3;
        }
        __syncthreads();
        if (t < RDIM) {
            ws[DP_OFF + b * RDIM + t] =
                part[0][t] + part[1][t] + part[2][t] + part[3][t];
        }
    }
}

// ---------------------------------------------------------------------------
// Launch B: out[n] = sum_ph qpart[ph][n] + sum_r fp16(dp[r]) * up[r][n]
// ---------------------------------------------------------------------------
__global__ __launch_bounds__(256) void reduce_kernel(const float* __restrict__ ws,
                                                     const float* __restrict__ upf,
                                                     float* __restrict__ out) {
    const int t = threadIdx.x;
    const int n = blockIdx.x * 256 + t;

    __shared__ float dps[RDIM];
    if (t < RDIM) {
        float d = 0.f;
        #pragma unroll
        for (int b = 0; b < PB; ++b) d += ws[DP_OFF + b * RDIM + t];
        dps[t] = __half2float(__float2half(d));
    }
    __syncthreads();

    float acc = 0.f;
    #pragma unroll 16
    for (int ph = 0; ph < KCHUNKS; ++ph) {
        acc += ws[(size_t)ph * NDIM + n];
    }
    float e = 0.f;
    #pragma unroll 8
    for (int r = 0; r < RDIM; ++r) {
        e = fmaf(dps[r], upf[(size_t)r * NDIM + n], e);
    }
    out[n] = acc + e;
}

// ---------------------------------------------------------------------------
// Fallback (r5-style zero-workspace) if ws_size < WS_NEED.
// ---------------------------------------------------------------------------
__global__ __launch_bounds__(256) void fused_fallback(const float* __restrict__ x,
                                                      const int* __restrict__ qw,
                                                      const float* __restrict__ scales,
                                                      const float* __restrict__ zeros,
                                                      const float* __restrict__ bias,
                                                      const float* __restrict__ down,
                                                      const float* __restrict__ up,
                                                      float* __restrict__ out) {
    const int t  = threadIdx.x;
    const int ph = blockIdx.y;
    const int n0 = blockIdx.x * FB_CPB + t * 4;

    if (ph < KCHUNKS) {
        __shared__ __align__(16) float xs[KPC];
        __shared__ float sxs;
        if (t < KPC / 4) {
            *(float4*)&xs[t * 4] = *(const float4*)&x[ph * KPC + t * 4];
        }
        __syncthreads();
        if (t < 64) {
            float s = xs[t * 4] + xs[t * 4 + 1] + xs[t * 4 + 2] + xs[t * 4 + 3];
            #pragma unroll
            for (int o = 32; o >= 1; o >>= 1) s += __shfl_down(s, o, 64);
            if (t == 0) sxs = s;
        }
        __syncthreads();
        const float Sxc = sxs;
        float a0 = 0.f, a1 = 0.f, a2 = 0.f, a3 = 0.f;
        const int* qp = qw + (size_t)(ph * KBPC) * NDIM + n0;
        for (int kb = 0; kb < KBPC; ++kb) {
            const int4 wv = *(const int4*)qp;
            qp += NDIM;
            const unsigned wx = (unsigned)wv.x, wy = (unsigned)wv.y;
            const unsigned wz = (unsigned)wv.z, ww = (unsigned)wv.w;
            const float* xr = &xs[kb * 8];
            #pragma unroll
            for (int j = 0; j < 8; ++j) {
                const float xj = xr[j];
                a0 = fmaf(xj, (float)((wx >> (4 * j)) & 0xFu), a0);
                a1 = fmaf(xj, (float)((wy >> (4 * j)) & 0xFu), a1);
                a2 = fmaf(xj, (float)((wz >> (4 * j)) & 0xFu), a2);
                a3 = fmaf(xj, (float)((ww >> (4 * j)) & 0xFu), a3);
            }
        }
        const float4 sc = *(const float4*)&scales[n0];
        const float4 zr = *(const float4*)&zeros[n0];
        float p0 = fmaf(sc.x, a0, -zr.x * Sxc);
        float p1 = fmaf(sc.y, a1, -zr.y * Sxc);
        float p2 = fmaf(sc.z, a2, -zr.z * Sxc);
        float p3 = fmaf(sc.w, a3, -zr.w * Sxc);
        if (ph == 0) {
            const float4 bi = *(const float4*)&bias[n0];
            p0 += bi.x; p1 += bi.y; p2 += bi.z; p3 += bi.w;
        }
        atomicAdd(&out[n0 + 0], p0);
        atomicAdd(&out[n0 + 1], p1);
        atomicAdd(&out[n0 + 2], p2);
        atomicAdd(&out[n0 + 3], p3);
    } else {
        const int r  = t & 63;
        const int w  = t >> 6;
        const int k0 = w * (KDIM / 4);
        float acc0 = 0.f, acc1 = 0.f;
        for (int k = k0; k < k0 + KDIM / 4; k += 2) {
            const float xv0 = __half2float(__float2half(x[k]));
            const float xv1 = __half2float(__float2half(x[k + 1]));
            acc0 = fmaf(xv0, down[(size_t)k * RDIM + r], acc0);
            acc1 = fmaf(xv1, down[(size_t)(k + 1) * RDIM + r], acc1);
        }
        __shared__ float part[4][64];
        part[w][r] = acc0 + acc1;
        __syncthreads();
        __shared__ float dp[RDIM];
        if (t < 64) {
            const float d = part[0][t] + part[1][t] + part[2][t] + part[3][t];
            dp[t] = __half2float(__float2half(d));
        }
        __syncthreads();
        float e0 = 0.f, e1 = 0.f, e2 = 0.f, e3 = 0.f;
        #pragma unroll 8
        for (int rr = 0; rr < RDIM; ++rr) {
            const float d = dp[rr];
            const float4 uv = *(const float4*)&up[(size_t)rr * NDIM + n0];
            e0 = fmaf(d, uv.x, e0);
            e1 = fmaf(d, uv.y, e1);
            e2 = fmaf(d, uv.z, e2);
            e3 = fmaf(d, uv.w, e3);
        }
        atomicAdd(&out[n0 + 0], e0);
        atomicAdd(&out[n0 + 1], e1);
        atomicAdd(&out[n0 + 2], e2);
        atomicAdd(&out[n0 + 3], e3);
    }
}

extern "C" void kernel_launch(void* const* d_in, const int* in_sizes, int n_in,
                              void* d_out, int out_size, void* d_ws, size_t ws_size,
                              hipStream_t stream) {
    const float* x      = (const float*)d_in[0];
    const int*   qw     = (const int*)d_in[1];
    const float* scales = (const float*)d_in[2];
    const float* zeros  = (const float*)d_in[3];
    const float* bias   = (const float*)d_in[4];
    const float* down   = (const float*)d_in[5];   // fp16 values in fp32 carrier
    const float* up     = (const float*)d_in[6];   // fp16 values in fp32 carrier
    float* out = (float*)d_out;
    float* ws  = (float*)d_ws;

    if (ws_size >= WS_NEED) {
        quant_kernel<<<dim3(NBLK, KCHUNKS + 1), 256, 0, stream>>>(
            x, qw, scales, zeros, bias, down, ws);
        reduce_kernel<<<NDIM / 256, 256, 0, stream>>>(ws, up, out);
    } else {
        hipMemsetAsync(out, 0, (size_t)NDIM * sizeof(float), stream);
        fused_fallback<<<dim3(FB_NBLK, KCHUNKS + 1), 256, 0, stream>>>(
            x, qw, scales, zeros, bias, down, up, out);
    }
}

// Round 18
// 29.873 us; speedup vs baseline: 2.4392x; 2.4392x over previous
//
#include <hip/hip_runtime.h>
#include <hip/hip_fp16.h>

// Quant4Linear + EoRA fused GEMV, MI355X — atomic-free two-launch design.
// REVERT to r16 (measured best: 30.17 us) after r17's contiguity probe
// regressed (72.9 us: 32-VGPR clamp + fewer waves serialized the load stream).
//
// y[n] = bias[n] + scales[n]*sum_k x[k]*q[k,n] - zeros[n]*Sx + sum_r fp16(dp[r])*up[r,n]
//
// PROVEN: down/up are fp16 values in FLOAT32 carriers; d_in dict-order; out fp32.
// Ledger: r5 283; r6 43.8 (ILP); r9 37.3 (atomic-free); r10 null (TLP+);
// r11 32.2 (v_dot2); r12 30.8 (KCHUNKS 32); r13 null (balance); r15 141
// (fusion REVERTED: device fences = per-XCD L2 writeback storm); r16 30.17
// (KCHUNKS 16, BEST); r17 72.9 (CPB 2048 REVERTED). Structural floor:
// 117MB qweight stream (not L3-retained, FETCH~109MB/dispatch) at ~78% of
// 6.3 TB/s copy ceiling + ~2us reduce + ~2us dispatch.

#define KDIM 8192
#define NDIM 28672
#define RDIM 64

#define KCHUNKS 16
#define KPC (KDIM / KCHUNKS)      // 512 k per quant chunk
#define KBPC (KPC / 8)            // 64 packed rows per chunk
#define CPB 1024                  // 256 threads x 4 cols
#define NBLK (NDIM / CPB)         // 28

#define PB 8                      // prep blocks
#define PKPB (KDIM / PB)          // 1024 k per prep block

#define QPART_FLOATS (KCHUNKS * NDIM)
#define DP_OFF QPART_FLOATS
#define WS_NEED ((QPART_FLOATS + PB * RDIM) * 4)

typedef _Float16 h2v __attribute__((ext_vector_type(2)));

// acc += fp16pair(up) . fp16pair(xp)   (fp32 accumulate)
__device__ __forceinline__ float dot2p(unsigned up, unsigned xp, float acc) {
#if __has_builtin(__builtin_amdgcn_fdot2)
    return __builtin_amdgcn_fdot2(__builtin_bit_cast(h2v, up),
                                  __builtin_bit_cast(h2v, xp), acc, false);
#else
    h2v a = __builtin_bit_cast(h2v, up);
    h2v b = __builtin_bit_cast(h2v, xp);
    return acc + (float)a.x * (float)b.x + (float)a.y * (float)b.y;
#endif
}

// ---------------------------------------------------------------------------
// Launch A: y<KCHUNKS -> quant chunk partials; y==KCHUNKS, x<PB -> dp partials.
// ---------------------------------------------------------------------------
__global__ __launch_bounds__(256, 8) void quant_kernel(const float* __restrict__ x,
                                                       const int* __restrict__ qw,
                                                       const float* __restrict__ scales,
                                                       const float* __restrict__ zeros,
                                                       const float* __restrict__ bias,
                                                       const float* __restrict__ down,
                                                       float* __restrict__ ws) {
    const int t  = threadIdx.x;
    const int ph = blockIdx.y;

    if (ph < KCHUNKS) {
        // ---------------- quant chunk: k in [ph*512, ph*512+512) ----------
        const int n0 = blockIdx.x * CPB + t * 4;
        const int* qp = qw + (size_t)(ph * KBPC) * NDIM + n0;

        // prefetch batch 0 BEFORE the staging barrier (LDS-independent)
        int4 v0[4];
        #pragma unroll
        for (int u = 0; u < 4; ++u) {
            v0[u] = *(const int4*)(qp + (size_t)u * NDIM);
        }

        // stage x as fp16 pairs: xsp[row*4 + j] = half2(xh[row*8+j], xh[row*8+j+4])
        __shared__ __align__(16) unsigned xsp[KBPC * 4];
        __shared__ float sxs;
        if (t < KBPC) {                       // 64 threads, one packed row each
            const int base = ph * KPC + t * 8;
            const float4 f0 = *(const float4*)&x[base];
            const float4 f1 = *(const float4*)&x[base + 4];
            h2v p0 = { (_Float16)f0.x, (_Float16)f1.x };
            h2v p1 = { (_Float16)f0.y, (_Float16)f1.y };
            h2v p2 = { (_Float16)f0.z, (_Float16)f1.z };
            h2v p3 = { (_Float16)f0.w, (_Float16)f1.w };
            xsp[t * 4 + 0] = __builtin_bit_cast(unsigned, p0);
            xsp[t * 4 + 1] = __builtin_bit_cast(unsigned, p1);
            xsp[t * 4 + 2] = __builtin_bit_cast(unsigned, p2);
            xsp[t * 4 + 3] = __builtin_bit_cast(unsigned, p3);
            float s = (float)p0.x + (float)p0.y + (float)p1.x + (float)p1.y +
                      (float)p2.x + (float)p2.y + (float)p3.x + (float)p3.y;
            s += __shfl_down(s, 32, 64);
            s += __shfl_down(s, 16, 64);
            s += __shfl_down(s, 8, 64);
            s += __shfl_down(s, 4, 64);
            s += __shfl_down(s, 2, 64);
            s += __shfl_down(s, 1, 64);
            if (t == 0) sxs = s;
        }
        __syncthreads();
        const float Sxh = sxs;

        const unsigned M = 0x000F000Fu;   // nibble pair (j, j+4)
        const unsigned E = 0x64006400u;   // fp16 exp 1024 -> value 1024+q

        float a0 = 0.f, a1 = 0.f, a2 = 0.f, a3 = 0.f;

        #define CONSUME(vv, g)                                                \
        {                                                                     \
            _Pragma("unroll")                                                 \
            for (int u = 0; u < 4; ++u) {                                     \
                const int row = (g) * 4 + u;                                  \
                const uint4 xp = *(const uint4*)&xsp[row * 4];                \
                const unsigned wx = (unsigned)vv[u].x;                        \
                const unsigned wy = (unsigned)vv[u].y;                        \
                const unsigned wz = (unsigned)vv[u].z;                        \
                const unsigned ww = (unsigned)vv[u].w;                        \
                a0 = dot2p((wx & M) | E, xp.x, a0);                           \
                a0 = dot2p(((wx >> 4) & M) | E, xp.y, a0);                    \
                a0 = dot2p(((wx >> 8) & M) | E, xp.z, a0);                    \
                a0 = dot2p(((wx >> 12) & M) | E, xp.w, a0);                   \
                a1 = dot2p((wy & M) | E, xp.x, a1);                           \
                a1 = dot2p(((wy >> 4) & M) | E, xp.y, a1);                    \
                a1 = dot2p(((wy >> 8) & M) | E, xp.z, a1);                    \
                a1 = dot2p(((wy >> 12) & M) | E, xp.w, a1);                   \
                a2 = dot2p((wz & M) | E, xp.x, a2);                           \
                a2 = dot2p(((wz >> 4) & M) | E, xp.y, a2);                    \
                a2 = dot2p(((wz >> 8) & M) | E, xp.z, a2);                    \
                a2 = dot2p(((wz >> 12) & M) | E, xp.w, a2);                   \
                a3 = dot2p((ww & M) | E, xp.x, a3);                           \
                a3 = dot2p(((ww >> 4) & M) | E, xp.y, a3);                    \
                a3 = dot2p(((ww >> 8) & M) | E, xp.z, a3);                    \
                a3 = dot2p(((ww >> 12) & M) | E, xp.w, a3);                   \
            }                                                                 \
        }

        CONSUME(v0, 0);
        #pragma unroll
        for (int g = 1; g < KBPC / 4; ++g) {
            int4 v[4];
            #pragma unroll
            for (int u = 0; u < 4; ++u) {
                v[u] = *(const int4*)(qp + (size_t)(g * 4 + u) * NDIM);
            }
            CONSUME(v, g);
        }
        #undef CONSUME

        // remove the 1024-offset:  sum x*q = acc - 1024*Sxh
        const float4 sc = *(const float4*)&scales[n0];
        const float4 zr = *(const float4*)&zeros[n0];
        const float corr = 1024.f * Sxh;
        float4 p;
        p.x = fmaf(sc.x, a0 - corr, -zr.x * Sxh);
        p.y = fmaf(sc.y, a1 - corr, -zr.y * Sxh);
        p.z = fmaf(sc.z, a2 - corr, -zr.z * Sxh);
        p.w = fmaf(sc.w, a3 - corr, -zr.w * Sxh);
        if (ph == 0) {
            const float4 bi = *(const float4*)&bias[n0];
            p.x += bi.x; p.y += bi.y; p.z += bi.z; p.w += bi.w;
        }
        *(float4*)&ws[(size_t)ph * NDIM + n0] = p;   // plain store, no atomics
    } else if (blockIdx.x < PB) {
        // ---------------- prep: dp partials for k-block b -----------------
        const int b = blockIdx.x;
        const int w = t >> 6;
        const int l = t & 63;
        const int grp = l >> 4;
        const int li = l & 15;

        __shared__ float xsp2[PKPB];
        {
            float4 v = *(const float4*)&x[b * PKPB + t * 4];
            v.x = __half2float(__float2half(v.x));
            v.y = __half2float(__float2half(v.y));
            v.z = __half2float(__float2half(v.z));
            v.w = __half2float(__float2half(v.w));
            *(float4*)&xsp2[t * 4] = v;
        }
        __syncthreads();

        const float* dbase = down + (size_t)b * PKPB * RDIM;
        float a0 = 0.f, a1 = 0.f, a2 = 0.f, a3 = 0.f;
        for (int i = 0; i < 64; i += 4) {
            float4 v[4];
            #pragma unroll
            for (int u = 0; u < 4; ++u) {
                const int q = (i + u) * 4 + w;
                v[u] = *(const float4*)&dbase[(size_t)q * 256 + l * 4];
            }
            #pragma unroll
            for (int u = 0; u < 4; ++u) {
                const int q = (i + u) * 4 + w;
                const float xv = xsp2[q * 4 + grp];
                a0 = fmaf(xv, v[u].x, a0);
                a1 = fmaf(xv, v[u].y, a1);
                a2 = fmaf(xv, v[u].z, a2);
                a3 = fmaf(xv, v[u].w, a3);
            }
        }

        a0 += __shfl_xor(a0, 16, 64); a0 += __shfl_xor(a0, 32, 64);
        a1 += __shfl_xor(a1, 16, 64); a1 += __shfl_xor(a1, 32, 64);
        a2 += __shfl_xor(a2, 16, 64); a2 += __shfl_xor(a2, 32, 64);
        a3 += __shfl_xor(a3, 16, 64); a3 += __shfl_xor(a3, 32, 64);

        __shared__ float part[4][RDIM];
        if (l < 16) {
            part[w][li * 4 + 0] = a0;
            part[w][li * 4 + 1] = a1;
            part[w][li * 4 + 2] = a2;
            part[w][li * 4 + 3] = a3;
        }
        __syncthreads();
        if (t < RDIM) {
            ws[DP_OFF + b * RDIM + t] =
                part[0][t] + part[1][t] + part[2][t] + part[3][t];
        }
    }
}

// ---------------------------------------------------------------------------
// Launch B: out[n] = sum_ph qpart[ph][n] + sum_r fp16(dp[r]) * up[r][n]
// ---------------------------------------------------------------------------
__global__ __launch_bounds__(256) void reduce_kernel(const float* __restrict__ ws,
                                                     const float* __restrict__ upf,
                                                     float* __restrict__ out) {
    const int t = threadIdx.x;
    const int n = blockIdx.x * 256 + t;

    __shared__ float dps[RDIM];
    if (t < RDIM) {
        float d = 0.f;
        #pragma unroll
        for (int b = 0; b < PB; ++b) d += ws[DP_OFF + b * RDIM + t];
        dps[t] = __half2float(__float2half(d));
    }
    __syncthreads();

    float acc = 0.f;
    #pragma unroll 16
    for (int ph = 0; ph < KCHUNKS; ++ph) {
        acc += ws[(size_t)ph * NDIM + n];
    }
    float e = 0.f;
    #pragma unroll 8
    for (int r = 0; r < RDIM; ++r) {
        e = fmaf(dps[r], upf[(size_t)r * NDIM + n], e);
    }
    out[n] = acc + e;
}

// ---------------------------------------------------------------------------
// Fallback (r5-style zero-workspace) if ws_size < WS_NEED.
// ---------------------------------------------------------------------------
__global__ __launch_bounds__(256) void fused_fallback(const float* __restrict__ x,
                                                      const int* __restrict__ qw,
                                                      const float* __restrict__ scales,
                                                      const float* __restrict__ zeros,
                                                      const float* __restrict__ bias,
                                                      const float* __restrict__ down,
                                                      const float* __restrict__ up,
                                                      float* __restrict__ out) {
    const int t  = threadIdx.x;
    const int ph = blockIdx.y;
    const int n0 = blockIdx.x * CPB + t * 4;

    if (ph < KCHUNKS) {
        __shared__ __align__(16) float xs[KPC];
        __shared__ float sxs;
        if (t < KPC / 4) {
            *(float4*)&xs[t * 4] = *(const float4*)&x[ph * KPC + t * 4];
        }
        __syncthreads();
        if (t < 64) {
            float s = 0.f;
            #pragma unroll
            for (int i = 0; i < KPC / 64; ++i) s += xs[t * (KPC / 64) + i];
            #pragma unroll
            for (int o = 32; o >= 1; o >>= 1) s += __shfl_down(s, o, 64);
            if (t == 0) sxs = s;
        }
        __syncthreads();
        const float Sxc = sxs;
        float a0 = 0.f, a1 = 0.f, a2 = 0.f, a3 = 0.f;
        const int* qp = qw + (size_t)(ph * KBPC) * NDIM + n0;
        for (int kb = 0; kb < KBPC; ++kb) {
            const int4 wv = *(const int4*)qp;
            qp += NDIM;
            const unsigned wx = (unsigned)wv.x, wy = (unsigned)wv.y;
            const unsigned wz = (unsigned)wv.z, ww = (unsigned)wv.w;
            const float* xr = &xs[kb * 8];
            #pragma unroll
            for (int j = 0; j < 8; ++j) {
                const float xj = xr[j];
                a0 = fmaf(xj, (float)((wx >> (4 * j)) & 0xFu), a0);
                a1 = fmaf(xj, (float)((wy >> (4 * j)) & 0xFu), a1);
                a2 = fmaf(xj, (float)((wz >> (4 * j)) & 0xFu), a2);
                a3 = fmaf(xj, (float)((ww >> (4 * j)) & 0xFu), a3);
            }
        }
        const float4 sc = *(const float4*)&scales[n0];
        const float4 zr = *(const float4*)&zeros[n0];
        float p0 = fmaf(sc.x, a0, -zr.x * Sxc);
        float p1 = fmaf(sc.y, a1, -zr.y * Sxc);
        float p2 = fmaf(sc.z, a2, -zr.z * Sxc);
        float p3 = fmaf(sc.w, a3, -zr.w * Sxc);
        if (ph == 0) {
            const float4 bi = *(const float4*)&bias[n0];
            p0 += bi.x; p1 += bi.y; p2 += bi.z; p3 += bi.w;
        }
        atomicAdd(&out[n0 + 0], p0);
        atomicAdd(&out[n0 + 1], p1);
        atomicAdd(&out[n0 + 2], p2);
        atomicAdd(&out[n0 + 3], p3);
    } else {
        const int r  = t & 63;
        const int w  = t >> 6;
        const int k0 = w * (KDIM / 4);
        float acc0 = 0.f, acc1 = 0.f;
        for (int k = k0; k < k0 + KDIM / 4; k += 2) {
            const float xv0 = __half2float(__float2half(x[k]));
            const float xv1 = __half2float(__float2half(x[k + 1]));
            acc0 = fmaf(xv0, down[(size_t)k * RDIM + r], acc0);
            acc1 = fmaf(xv1, down[(size_t)(k + 1) * RDIM + r], acc1);
        }
        __shared__ float part[4][64];
        part[w][r] = acc0 + acc1;
        __syncthreads();
        __shared__ float dp[RDIM];
        if (t < 64) {
            const float d = part[0][t] + part[1][t] + part[2][t] + part[3][t];
            dp[t] = __half2float(__float2half(d));
        }
        __syncthreads();
        float e0 = 0.f, e1 = 0.f, e2 = 0.f, e3 = 0.f;
        #pragma unroll 8
        for (int rr = 0; rr < RDIM; ++rr) {
            const float d = dp[rr];
            const float4 uv = *(const float4*)&up[(size_t)rr * NDIM + n0];
            e0 = fmaf(d, uv.x, e0);
            e1 = fmaf(d, uv.y, e1);
            e2 = fmaf(d, uv.z, e2);
            e3 = fmaf(d, uv.w, e3);
        }
        atomicAdd(&out[n0 + 0], e0);
        atomicAdd(&out[n0 + 1], e1);
        atomicAdd(&out[n0 + 2], e2);
        atomicAdd(&out[n0 + 3], e3);
    }
}

extern "C" void kernel_launch(void* const* d_in, const int* in_sizes, int n_in,
                              void* d_out, int out_size, void* d_ws, size_t ws_size,
                              hipStream_t stream) {
    const float* x      = (const float*)d_in[0];
    const int*   qw     = (const int*)d_in[1];
    const float* scales = (const float*)d_in[2];
    const float* zeros  = (const float*)d_in[3];
    const float* bias   = (const float*)d_in[4];
    const float* down   = (const float*)d_in[5];   // fp16 values in fp32 carrier
    const float* up     = (const float*)d_in[6];   // fp16 values in fp32 carrier
    float* out = (float*)d_out;
    float* ws  = (float*)d_ws;

    if (ws_size >= WS_NEED) {
        quant_kernel<<<dim3(NBLK, KCHUNKS + 1), 256, 0, stream>>>(
            x, qw, scales, zeros, bias, down, ws);
        reduce_kernel<<<NDIM / 256, 256, 0, stream>>>(ws, up, out);
    } else {
        hipMemsetAsync(out, 0, (size_t)NDIM * sizeof(float), stream);
        fused_fallback<<<dim3(NBLK, KCHUNKS + 1), 256, 0, stream>>>(
            x, qw, scales, zeros, bias, down, up, out);
    }
}